// Round 16
// baseline (413.878 us; speedup 1.0000x reference)
//
#include <hip/hip_runtime.h>
#include <hip/hip_bf16.h>

#define NN 50000
#define NE 800000
#define REP 8

typedef short short8 __attribute__((ext_vector_type(8)));
typedef float f32x4 __attribute__((ext_vector_type(4)));
typedef unsigned short ushort_t;

// ---- truncation-based bf16 hi/lo split helpers ----
static __device__ __forceinline__ unsigned bits(float f) { return __float_as_uint(f); }
static __device__ __forceinline__ float hi_f(float v) {
  return __uint_as_float(bits(v) & 0xFFFF0000u);
}
static __device__ __forceinline__ ushort_t hi_u(float v) { return (ushort_t)(bits(v) >> 16); }
static __device__ __forceinline__ unsigned pack_hi(float v0, float v1) {
  return (bits(v0) >> 16) | (bits(v1) & 0xFFFF0000u);
}
static __device__ __forceinline__ unsigned pack_lo(float v0, float v1) {
  float l0 = v0 - hi_f(v0), l1 = v1 - hi_f(v1);
  return (bits(l0) >> 16) | (bits(l1) & 0xFFFF0000u);
}

#define MFMA(a, b, c) __builtin_amdgcn_mfma_f32_16x16x32_bf16(a, b, c, 0, 0, 0)

// ---------------- kA: weight-pack hi-only (t < 4096) + CSR offsets (all threads).
__global__ __launch_bounds__(256) void kA_pack_off(
    const float* __restrict__ Wn, const float* __restrict__ Wc,
    const float* __restrict__ Wu, const float* __restrict__ base_w,
    const float* __restrict__ spline_w, const float* __restrict__ scaler,
    const int* __restrict__ seg,
    ushort_t* __restrict__ p1h, ushort_t* __restrict__ p2h,
    ushort_t* __restrict__ p3h, int* __restrict__ off) {
  int t = blockIdx.x * 256 + threadIdx.x;
  if (t < 4096) {
    int l = t & 63, lm = l & 15, lk = l >> 4;
    if (t < 2048) {
      int nt = t >> 8, ks = (t >> 6) & 3;
      int h = nt * 16 + lm;
#pragma unroll
      for (int j = 0; j < 8; ++j) {
        int f = ks * 32 + lk * 8 + j;
        float v = (f < 64) ? Wn[h * 64 + f] : Wc[h * 64 + (f - 64)];
        p1h[t * 8 + j] = hi_u(v);
      }
    }
    if (t < 1024) {
      int nt = t >> 8, ks = (t >> 6) & 3;
      int o = nt * 16 + lm;
#pragma unroll
      for (int j = 0; j < 8; ++j) {
        int hh = ks * 32 + lk * 8 + j;
        p2h[t * 8 + j] = hi_u(Wu[o * 128 + hh]);
      }
    }
    if (t < 3072) {
      int nt = t / 768, ks = (t >> 6) % 12;
      int o = nt * 16 + lm;
#pragma unroll
      for (int j = 0; j < 8; ++j) {
        int k = ks * 32 + lk * 8 + j;
        int i = k / 6, c = k % 6;
        float v = (c == 0) ? base_w[o * 64 + i]
                           : spline_w[(o * 64 + i) * 5 + (c - 1)] * scaler[o * 64 + i];
        p3h[t * 8 + j] = hi_u(v);
      }
    }
  }
  int e = t;
  if (e < NE) {
    int s1 = seg[e];
    if (e == 0) {
      for (int n = 0; n <= s1; ++n) off[n] = 0;
    } else {
      int s0 = seg[e - 1];
      for (int n = s0 + 1; n <= s1; ++n) off[n] = e;
    }
    if (e == NE - 1) {
      for (int n = s1 + 1; n <= NN; ++n) off[n] = NE;
    }
  }
}

// ---------------- k1: per-node edge aggregation (one wave per node); Sp as bf16 hi/lo.
// AT ROOFLINE: 205 MB ctx stream @ ~5.9 TB/s (94% of measured 6.3 TB/s ceiling).
__global__ __launch_bounds__(256) void k1_edge_agg(
    const float* __restrict__ contexts, const float* __restrict__ attn,
    const int* __restrict__ off, ushort_t* __restrict__ Sph,
    ushort_t* __restrict__ Spl, float* __restrict__ aprime,
    float* __restrict__ degw) {
  int n = blockIdx.x * 4 + (threadIdx.x >> 6);
  int lane = threadIdx.x & 63;
  if (n >= NN) return;
  int s = off[n];
  int e_end = off[n + 1];
  int deg_i = e_end - s;

  int sub = lane >> 4;
  int fq = lane & 15;
  const float4* ctx4 = (const float4*)contexts;

  float4 S = make_float4(0.f, 0.f, 0.f, 0.f);
  float A = 0.f;
  if (deg_i > 0) {
    int last = e_end - 1;
    for (int e0 = s; e0 < e_end; e0 += 16) {
      float a[4];
      float4 c[4];
#pragma unroll
      for (int u = 0; u < 4; ++u) {
        int eu = e0 + 4 * u + sub;
        a[u] = (eu < e_end) ? attn[eu] : 0.f;
        c[u] = ctx4[(size_t)min(eu, last) * 16 + fq];
      }
#pragma unroll
      for (int u = 0; u < 4; ++u) {
        S.x += a[u] * c[u].x;
        S.y += a[u] * c[u].y;
        S.z += a[u] * c[u].z;
        S.w += a[u] * c[u].w;
        A += a[u];
      }
    }
  }
#pragma unroll
  for (int m = 16; m <= 32; m <<= 1) {
    S.x += __shfl_xor(S.x, m);
    S.y += __shfl_xor(S.y, m);
    S.z += __shfl_xor(S.z, m);
    S.w += __shfl_xor(S.w, m);
    A += __shfl_xor(A, m);
  }
  float deg = (float)deg_i;
  float inv = 1.f / fmaxf(deg, 1.f);
  if (lane < 16) {
    float ox = S.x * inv, oy = S.y * inv, oz = S.z * inv, ow = S.w * inv;
    uint2 hp, lp;
    hp.x = pack_hi(ox, oy);
    hp.y = pack_hi(oz, ow);
    lp.x = pack_lo(ox, oy);
    lp.y = pack_lo(oz, ow);
    *(uint2*)&Sph[(size_t)n * 64 + lane * 4] = hp;
    *(uint2*)&Spl[(size_t)n * 64 + lane * 4] = lp;
  }
  if (lane == 0) { aprime[n] = A * inv; degw[n] = deg; }
}

// ---------------- k234: R15 structure EXACTLY, wrapped in REP=8 (idempotent) so the
// dispatch outranks harness fills and its counters surface. ONE change this round.
__global__ __launch_bounds__(256, 4) void k234(
    const float* __restrict__ x,
    const ushort_t* __restrict__ Sph, const ushort_t* __restrict__ Spl,
    const float* __restrict__ aprime, const float* __restrict__ degw,
    const float* __restrict__ bn, const float* __restrict__ bc,
    const float* __restrict__ bu,
    const ushort_t* __restrict__ p1h, const ushort_t* __restrict__ p2h,
    const ushort_t* __restrict__ p3h,
    const float* __restrict__ gridp, float* __restrict__ out) {
  __shared__ __align__(16) unsigned char arena[32768];
  __shared__ float ap[64], degl[64];
  ushort_t* Uh = (ushort_t*)arena;             // [64][128] swizzled
  ushort_t* Ul = (ushort_t*)(arena + 16384);   // [64][128] swizzled; T overlays after GEMM1
  ushort_t* Vh = (ushort_t*)arena;             // [32][392], overlays everything (post-GEMM2)

  int tid = threadIdx.x;
  int n0 = blockIdx.x * 64;
  int w = tid >> 6, l = tid & 63;
  int lm = l & 15, lk = l >> 4;
  const short8* P1h = (const short8*)p1h;
  const short8* P2h = (const short8*)p2h;
  const short8* P3h = (const short8*)p3h;

  // ---- hoist only GEMM2 B (16 VGPR)
  short8 B2[4];
#pragma unroll
  for (int ks = 0; ks < 4; ++ks) B2[ks] = P2h[(w * 4 + ks) * 64 + l];

#pragma unroll 1
  for (int rep = 0; rep < REP; ++rep) {
    __syncthreads();  // guard: prior rep's epilogue reads (degl/Vh) complete

    // ---- stage: x packed on the fly, Sp copied (already hi/lo). Swizzled dest.
    {
      const float4* x4 = (const float4*)x;
      const uint4* Sh4 = (const uint4*)Sph;
      const uint4* Sl4 = (const uint4*)Spl;
      for (int q = tid; q < 1024; q += 256) {
        int row = q >> 4, slot = q & 15;
        int n = n0 + row;
        int idx = (row * 128 + slot * 8) ^ ((row & 7) << 3);
        if (slot < 8) {
          float4 a = make_float4(0.f, 0.f, 0.f, 0.f), b = a;
          if (n < NN) {
            a = x4[(size_t)n * 16 + slot * 2];
            b = x4[(size_t)n * 16 + slot * 2 + 1];
          }
          uint4 hp, lp;
          hp.x = pack_hi(a.x, a.y); hp.y = pack_hi(a.z, a.w);
          hp.z = pack_hi(b.x, b.y); hp.w = pack_hi(b.z, b.w);
          lp.x = pack_lo(a.x, a.y); lp.y = pack_lo(a.z, a.w);
          lp.z = pack_lo(b.x, b.y); lp.w = pack_lo(b.z, b.w);
          *(uint4*)&Uh[idx] = hp;
          *(uint4*)&Ul[idx] = lp;
        } else {
          uint4 vh = make_uint4(0u, 0u, 0u, 0u), vl = vh;
          if (n < NN) {
            vh = Sh4[(size_t)n * 8 + (slot & 7)];
            vl = Sl4[(size_t)n * 8 + (slot & 7)];
          }
          *(uint4*)&Uh[idx] = vh;
          *(uint4*)&Ul[idx] = vl;
        }
      }
    }
    if (tid < 64) {
      int n = n0 + tid;
      ap[tid] = (n < NN) ? aprime[n] : 0.f;
      degl[tid] = (n < NN) ? degw[n] : 1.f;
    }
    __syncthreads();  // A: U tile complete

    int swzA = (lm & 7) << 3;

    // ---- GEMM1 (2-term): wave w -> h-tiles {2w,2w+1}, all 4 m-tiles. B1 from L2 in-loop.
    f32x4 acc1[2][4];
#pragma unroll
    for (int q = 0; q < 2; ++q)
#pragma unroll
      for (int mt = 0; mt < 4; ++mt) acc1[q][mt] = (f32x4){0.f, 0.f, 0.f, 0.f};
#pragma unroll
    for (int ks = 0; ks < 4; ++ks) {
      short8 bh0 = P1h[((2 * w + 0) * 4 + ks) * 64 + l];
      short8 bh1 = P1h[((2 * w + 1) * 4 + ks) * 64 + l];
#pragma unroll
      for (int mt = 0; mt < 4; ++mt) {
        int ai = ((mt * 16 + lm) * 128 + ks * 32 + lk * 8) ^ swzA;
        short8 ah = *(const short8*)&Uh[ai];
        short8 al = *(const short8*)&Ul[ai];
        acc1[0][mt] = MFMA(ah, bh0, acc1[0][mt]);
        acc1[0][mt] = MFMA(al, bh0, acc1[0][mt]);
        acc1[1][mt] = MFMA(ah, bh1, acc1[1][mt]);
        acc1[1][mt] = MFMA(al, bh1, acc1[1][mt]);
      }
    }
    __syncthreads();  // B1: all GEMM1 reads of Uh/Ul complete (T will overlay Ul)

    // ---- bias + T-write (hi-only) into Ul region
#pragma unroll
    for (int q = 0; q < 2; ++q) {
      int h = (2 * w + q) * 16 + lm;
      float bnv = bn[h], bcv = bc[h];
#pragma unroll
      for (int mt = 0; mt < 4; ++mt) {
#pragma unroll
        for (int r = 0; r < 4; ++r) {
          int node = mt * 16 + lk * 4 + r;
          float t = acc1[q][mt][r] + bnv + ap[node] * bcv;
          Ul[(node * 128 + h) ^ ((node & 7) << 3)] = hi_u(t);
        }
      }
    }
    __syncthreads();  // B2: T ready

    // ---- GEMM2 (1-term): wave w -> o-tile w, 4 m-tiles. T from Ul region.
    f32x4 acc2[4];
#pragma unroll
    for (int mt = 0; mt < 4; ++mt) acc2[mt] = (f32x4){0.f, 0.f, 0.f, 0.f};
#pragma unroll
    for (int ks = 0; ks < 4; ++ks) {
#pragma unroll
      for (int mt = 0; mt < 4; ++mt) {
        int ai = ((mt * 16 + lm) * 128 + ks * 32 + lk * 8) ^ swzA;
        short8 ah = *(const short8*)&Ul[ai];
        acc2[mt] = MFMA(ah, B2[ks], acc2[mt]);
      }
    }
    __syncthreads();  // C: all T reads done (V will overlay the whole arena)

    // ---- spline constants (deferred to cap VGPR in GEMM phases)
    float g[8];
#pragma unroll
    for (int j = 0; j < 8; ++j) g[j] = gridp[j];
    float r1[7], r2[6];
#pragma unroll
    for (int j = 0; j < 7; ++j) r1[j] = 1.f / (g[j + 1] - g[j]);
#pragma unroll
    for (int j = 0; j < 6; ++j) r2[j] = 1.f / (g[j + 2] - g[j]);
    float buv = bu[w * 16 + lm];

    // ---- two 32-node halves: transform -> Vh (hi-only), KAN GEMM (B3 from L2), store
#pragma unroll
    for (int half = 0; half < 2; ++half) {
#pragma unroll
      for (int ms = 0; ms < 2; ++ms) {
        int mt = half * 2 + ms;
#pragma unroll
        for (int r = 0; r < 4; ++r) {
          float xv = acc2[mt][r] + buv;
          float sil = xv / (1.f + __expf(-xv));
          float b0[7], b1[6], b2[5];
#pragma unroll
          for (int q = 0; q < 7; ++q) b0[q] = (xv >= g[q] && xv < g[q + 1]) ? 1.f : 0.f;
#pragma unroll
          for (int q = 0; q < 6; ++q)
            b1[q] = (xv - g[q]) * r1[q] * b0[q] + (g[q + 2] - xv) * r1[q + 1] * b0[q + 1];
#pragma unroll
          for (int q = 0; q < 5; ++q)
            b2[q] = (xv - g[q]) * r2[q] * b1[q] + (g[q + 3] - xv) * r2[q + 1] * b1[q + 1];
          int ln = ms * 16 + lk * 4 + r;
          int base = ln * 392 + (w * 16 + lm) * 6;
          *(unsigned*)&Vh[base + 0] = pack_hi(sil, b2[0]);
          *(unsigned*)&Vh[base + 2] = pack_hi(b2[1], b2[2]);
          *(unsigned*)&Vh[base + 4] = pack_hi(b2[3], b2[4]);
        }
      }
      __syncthreads();  // V ready

      // KAN GEMM (1-term): wave w -> o-tile w, 2 s-tiles. B3 streamed from L2.
      f32x4 accK[2];
      accK[0] = (f32x4){0.f, 0.f, 0.f, 0.f};
      accK[1] = (f32x4){0.f, 0.f, 0.f, 0.f};
#pragma unroll
      for (int ks = 0; ks < 12; ++ks) {
        short8 bh = P3h[(w * 12 + ks) * 64 + l];
#pragma unroll
        for (int s = 0; s < 2; ++s) {
          short8 ah = *(const short8*)&Vh[(s * 16 + lm) * 392 + ks * 32 + lk * 8];
          accK[s] = MFMA(ah, bh, accK[s]);
        }
      }
      __syncthreads();  // V reads done before half1 overwrites (and before next rep)

#pragma unroll
      for (int s = 0; s < 2; ++s) {
        int o = w * 16 + lm;
#pragma unroll
        for (int r = 0; r < 4; ++r) {
          int node = half * 32 + s * 16 + lk * 4 + r;
          int n = n0 + node;
          if (n < NN) {
            float val = accK[s][r];
            if (degl[node] <= 0.f) val = x[(size_t)n * 64 + o];
            out[(size_t)n * 64 + o] = val;
          }
        }
      }
    }
  }
}

extern "C" void kernel_launch(void* const* d_in, const int* in_sizes, int n_in,
                              void* d_out, int out_size, void* d_ws, size_t ws_size,
                              hipStream_t stream) {
  const float* x        = (const float*)d_in[0];
  const float* contexts = (const float*)d_in[1];
  const float* attn     = (const float*)d_in[2];
  const int*   seg      = (const int*)d_in[3];
  const float* Wn       = (const float*)d_in[4];
  const float* bn       = (const float*)d_in[5];
  const float* Wc       = (const float*)d_in[6];
  const float* bc       = (const float*)d_in[7];
  const float* Wu       = (const float*)d_in[8];
  const float* bu       = (const float*)d_in[9];
  const float* base_w   = (const float*)d_in[10];
  const float* spline_w = (const float*)d_in[11];
  const float* scaler   = (const float*)d_in[12];
  const float* gridp    = (const float*)d_in[13];
  float* out = (float*)d_out;

  ushort_t* us  = (ushort_t*)d_ws;
  ushort_t* Sph = us;                    // 3,200,000
  ushort_t* Spl = Sph + 3200000;         // 3,200,000
  ushort_t* p1h = Spl + 3200000;         // 16384
  ushort_t* p2h = p1h + 16384;           // 8192
  ushort_t* p3h = p2h + 8192;            // 24576
  float* aprime = (float*)(p3h + 24576); // 50,000
  float* degw   = aprime + 50000;        // 50,000
  int*   off    = (int*)(degw + 50000);  // 50,001

  kA_pack_off<<<3125, 256, 0, stream>>>(Wn, Wc, Wu, base_w, spline_w, scaler, seg,
                                        p1h, p2h, p3h, off);
  k1_edge_agg<<<12500, 256, 0, stream>>>(contexts, attn, off, Sph, Spl, aprime, degw);
  k234<<<782, 256, 0, stream>>>(x, Sph, Spl, aprime, degw, bn, bc, bu,
                                p1h, p2h, p3h, gridp, out);
}

// Round 17
// 66.338 us; speedup vs baseline: 6.2389x; 6.2389x over previous
//
#include <hip/hip_runtime.h>
#include <hip/hip_bf16.h>

#define NN 50000
#define NE 800000

typedef short short8 __attribute__((ext_vector_type(8)));
typedef float f32x4 __attribute__((ext_vector_type(4)));
typedef unsigned short ushort_t;

// ---- truncation-based bf16 hi/lo split helpers ----
static __device__ __forceinline__ unsigned bits(float f) { return __float_as_uint(f); }
static __device__ __forceinline__ float hi_f(float v) {
  return __uint_as_float(bits(v) & 0xFFFF0000u);
}
static __device__ __forceinline__ ushort_t hi_u(float v) { return (ushort_t)(bits(v) >> 16); }
static __device__ __forceinline__ unsigned pack_hi(float v0, float v1) {
  return (bits(v0) >> 16) | (bits(v1) & 0xFFFF0000u);
}
static __device__ __forceinline__ unsigned pack_lo(float v0, float v1) {
  float l0 = v0 - hi_f(v0), l1 = v1 - hi_f(v1);
  return (bits(l0) >> 16) | (bits(l1) & 0xFFFF0000u);
}

#define MFMA(a, b, c) __builtin_amdgcn_mfma_f32_16x16x32_bf16(a, b, c, 0, 0, 0)

// ---------------- kA: weight-pack hi-only (t < 4096) + CSR offsets (all threads).
__global__ __launch_bounds__(256) void kA_pack_off(
    const float* __restrict__ Wn, const float* __restrict__ Wc,
    const float* __restrict__ Wu, const float* __restrict__ base_w,
    const float* __restrict__ spline_w, const float* __restrict__ scaler,
    const int* __restrict__ seg,
    ushort_t* __restrict__ p1h, ushort_t* __restrict__ p2h,
    ushort_t* __restrict__ p3h, int* __restrict__ off) {
  int t = blockIdx.x * 256 + threadIdx.x;
  if (t < 4096) {
    int l = t & 63, lm = l & 15, lk = l >> 4;
    if (t < 2048) {
      int nt = t >> 8, ks = (t >> 6) & 3;
      int h = nt * 16 + lm;
#pragma unroll
      for (int j = 0; j < 8; ++j) {
        int f = ks * 32 + lk * 8 + j;
        float v = (f < 64) ? Wn[h * 64 + f] : Wc[h * 64 + (f - 64)];
        p1h[t * 8 + j] = hi_u(v);
      }
    }
    if (t < 1024) {
      int nt = t >> 8, ks = (t >> 6) & 3;
      int o = nt * 16 + lm;
#pragma unroll
      for (int j = 0; j < 8; ++j) {
        int hh = ks * 32 + lk * 8 + j;
        p2h[t * 8 + j] = hi_u(Wu[o * 128 + hh]);
      }
    }
    if (t < 3072) {
      int nt = t / 768, ks = (t >> 6) % 12;
      int o = nt * 16 + lm;
#pragma unroll
      for (int j = 0; j < 8; ++j) {
        int k = ks * 32 + lk * 8 + j;
        int i = k / 6, c = k % 6;
        float v = (c == 0) ? base_w[o * 64 + i]
                           : spline_w[(o * 64 + i) * 5 + (c - 1)] * scaler[o * 64 + i];
        p3h[t * 8 + j] = hi_u(v);
      }
    }
  }
  int e = t;
  if (e < NE) {
    int s1 = seg[e];
    if (e == 0) {
      for (int n = 0; n <= s1; ++n) off[n] = 0;
    } else {
      int s0 = seg[e - 1];
      for (int n = s0 + 1; n <= s1; ++n) off[n] = e;
    }
    if (e == NE - 1) {
      for (int n = s1 + 1; n <= NN; ++n) off[n] = NE;
    }
  }
}

// ---------------- k1: per-node edge aggregation; Sp as bf16 HI-ONLY (byte diet).
// Read side at roofline: 205 MB ctx stream @ ~5.9 TB/s.
__global__ __launch_bounds__(256) void k1_edge_agg(
    const float* __restrict__ contexts, const float* __restrict__ attn,
    const int* __restrict__ off, ushort_t* __restrict__ Sph,
    float* __restrict__ aprime, float* __restrict__ degw) {
  int n = blockIdx.x * 4 + (threadIdx.x >> 6);
  int lane = threadIdx.x & 63;
  if (n >= NN) return;
  int s = off[n];
  int e_end = off[n + 1];
  int deg_i = e_end - s;

  int sub = lane >> 4;
  int fq = lane & 15;
  const float4* ctx4 = (const float4*)contexts;

  float4 S = make_float4(0.f, 0.f, 0.f, 0.f);
  float A = 0.f;
  if (deg_i > 0) {
    int last = e_end - 1;
    for (int e0 = s; e0 < e_end; e0 += 16) {
      float a[4];
      float4 c[4];
#pragma unroll
      for (int u = 0; u < 4; ++u) {
        int eu = e0 + 4 * u + sub;
        a[u] = (eu < e_end) ? attn[eu] : 0.f;
        c[u] = ctx4[(size_t)min(eu, last) * 16 + fq];
      }
#pragma unroll
      for (int u = 0; u < 4; ++u) {
        S.x += a[u] * c[u].x;
        S.y += a[u] * c[u].y;
        S.z += a[u] * c[u].z;
        S.w += a[u] * c[u].w;
        A += a[u];
      }
    }
  }
#pragma unroll
  for (int m = 16; m <= 32; m <<= 1) {
    S.x += __shfl_xor(S.x, m);
    S.y += __shfl_xor(S.y, m);
    S.z += __shfl_xor(S.z, m);
    S.w += __shfl_xor(S.w, m);
    A += __shfl_xor(A, m);
  }
  float deg = (float)deg_i;
  float inv = 1.f / fmaxf(deg, 1.f);
  if (lane < 16) {
    float ox = S.x * inv, oy = S.y * inv, oz = S.z * inv, ow = S.w * inv;
    uint2 hp;
    hp.x = pack_hi(ox, oy);
    hp.y = pack_hi(oz, ow);
    *(uint2*)&Sph[(size_t)n * 64 + lane * 4] = hp;
  }
  if (lane == 0) { aprime[n] = A * inv; degw[n] = deg; }
}

// ---------------- k234: byte-diet pipeline. 4-wave N-split, arena 32KB (4 blocks/CU).
// Uh[64][128] hi; Ul[64][128] but only x-lo (cols 0..63) written/used (ks<2).
// T overlays Ul. V [32][384] XOR-swizzled overlays Uh+part of Ul.
// ot [32][64] f32 XOR-swizzled overlays T-tail -> full-line coalesced out writes.
__global__ __launch_bounds__(256, 4) void k234(
    const float* __restrict__ x,
    const ushort_t* __restrict__ Sph,
    const float* __restrict__ aprime, const float* __restrict__ degw,
    const float* __restrict__ bn, const float* __restrict__ bc,
    const float* __restrict__ bu,
    const ushort_t* __restrict__ p1h, const ushort_t* __restrict__ p2h,
    const ushort_t* __restrict__ p3h,
    const float* __restrict__ gridp, float* __restrict__ out) {
  __shared__ __align__(16) unsigned char arena[32768];
  __shared__ float ap[64], degl[64];
  ushort_t* Uh = (ushort_t*)arena;             // [64][128] swizzled (hi)
  ushort_t* Ul = (ushort_t*)(arena + 16384);   // [64][128]: x-lo in cols 0..63; T overlays
  ushort_t* Vh = (ushort_t*)arena;             // [32][384] per-uint XOR swizzle
  float*    ot = (float*)(arena + 24576);      // [32][64] f32 XOR swizzle (T-tail region)

  int tid = threadIdx.x;
  int n0 = blockIdx.x * 64;
  int w = tid >> 6, l = tid & 63;
  int lm = l & 15, lk = l >> 4;
  const short8* P1h = (const short8*)p1h;
  const short8* P2h = (const short8*)p2h;
  const short8* P3h = (const short8*)p3h;

  // ---- hoist only GEMM2 B (16 VGPR)
  short8 B2[4];
#pragma unroll
  for (int ks = 0; ks < 4; ++ks) B2[ks] = P2h[(w * 4 + ks) * 64 + l];

  // ---- stage: x (hi+lo), Sp (hi only). Swizzled dest.
  {
    const float4* x4 = (const float4*)x;
    const uint4* Sh4 = (const uint4*)Sph;
    for (int q = tid; q < 1024; q += 256) {
      int row = q >> 4, slot = q & 15;
      int n = n0 + row;
      int idx = (row * 128 + slot * 8) ^ ((row & 7) << 3);
      if (slot < 8) {
        float4 a = make_float4(0.f, 0.f, 0.f, 0.f), b = a;
        if (n < NN) {
          a = x4[(size_t)n * 16 + slot * 2];
          b = x4[(size_t)n * 16 + slot * 2 + 1];
        }
        uint4 hp, lp;
        hp.x = pack_hi(a.x, a.y); hp.y = pack_hi(a.z, a.w);
        hp.z = pack_hi(b.x, b.y); hp.w = pack_hi(b.z, b.w);
        lp.x = pack_lo(a.x, a.y); lp.y = pack_lo(a.z, a.w);
        lp.z = pack_lo(b.x, b.y); lp.w = pack_lo(b.z, b.w);
        *(uint4*)&Uh[idx] = hp;
        *(uint4*)&Ul[idx] = lp;  // x-lo only (cols 0..63)
      } else {
        uint4 vh = make_uint4(0u, 0u, 0u, 0u);
        if (n < NN) vh = Sh4[(size_t)n * 8 + (slot & 7)];
        *(uint4*)&Uh[idx] = vh;  // no Sp-lo
      }
    }
  }
  if (tid < 64) {
    int n = n0 + tid;
    ap[tid] = (n < NN) ? aprime[n] : 0.f;
    degl[tid] = (n < NN) ? degw[n] : 1.f;
  }
  __syncthreads();  // A: U tile complete

  int swzA = (lm & 7) << 3;

  // ---- GEMM1: wave w -> h-tiles {2w,2w+1}, 4 m-tiles. hi-term all K, lo-term x-half only.
  f32x4 acc1[2][4];
#pragma unroll
  for (int q = 0; q < 2; ++q)
#pragma unroll
    for (int mt = 0; mt < 4; ++mt) acc1[q][mt] = (f32x4){0.f, 0.f, 0.f, 0.f};
#pragma unroll
  for (int ks = 0; ks < 4; ++ks) {
    short8 bh0 = P1h[((2 * w + 0) * 4 + ks) * 64 + l];
    short8 bh1 = P1h[((2 * w + 1) * 4 + ks) * 64 + l];
#pragma unroll
    for (int mt = 0; mt < 4; ++mt) {
      int ai = ((mt * 16 + lm) * 128 + ks * 32 + lk * 8) ^ swzA;
      short8 ah = *(const short8*)&Uh[ai];
      acc1[0][mt] = MFMA(ah, bh0, acc1[0][mt]);
      acc1[1][mt] = MFMA(ah, bh1, acc1[1][mt]);
      if (ks < 2) {  // x-lo contribution only
        short8 al = *(const short8*)&Ul[ai];
        acc1[0][mt] = MFMA(al, bh0, acc1[0][mt]);
        acc1[1][mt] = MFMA(al, bh1, acc1[1][mt]);
      }
    }
  }
  __syncthreads();  // B1: all GEMM1 reads of Uh/Ul complete (T overlays Ul)

  // ---- bias + T-write (hi-only) into Ul region
#pragma unroll
  for (int q = 0; q < 2; ++q) {
    int h = (2 * w + q) * 16 + lm;
    float bnv = bn[h], bcv = bc[h];
#pragma unroll
    for (int mt = 0; mt < 4; ++mt) {
#pragma unroll
      for (int r = 0; r < 4; ++r) {
        int node = mt * 16 + lk * 4 + r;
        float t = acc1[q][mt][r] + bnv + ap[node] * bcv;
        Ul[(node * 128 + h) ^ ((node & 7) << 3)] = hi_u(t);
      }
    }
  }
  __syncthreads();  // B2: T ready

  // ---- GEMM2 (1-term): wave w -> o-tile w, 4 m-tiles. T from Ul region.
  f32x4 acc2[4];
#pragma unroll
  for (int mt = 0; mt < 4; ++mt) acc2[mt] = (f32x4){0.f, 0.f, 0.f, 0.f};
#pragma unroll
  for (int ks = 0; ks < 4; ++ks) {
#pragma unroll
    for (int mt = 0; mt < 4; ++mt) {
      int ai = ((mt * 16 + lm) * 128 + ks * 32 + lk * 8) ^ swzA;
      short8 ah = *(const short8*)&Ul[ai];
      acc2[mt] = MFMA(ah, B2[ks], acc2[mt]);
    }
  }
  __syncthreads();  // C: all T reads done (V/ot will overlay the arena)

  // ---- spline constants (deferred to cap VGPR in GEMM phases)
  float g[8];
#pragma unroll
  for (int j = 0; j < 8; ++j) g[j] = gridp[j];
  float r1[7], r2[6];
#pragma unroll
  for (int j = 0; j < 7; ++j) r1[j] = 1.f / (g[j + 1] - g[j]);
#pragma unroll
  for (int j = 0; j < 6; ++j) r2[j] = 1.f / (g[j + 2] - g[j]);
  float buv = bu[w * 16 + lm];

  // ---- two 32-node halves: transform -> Vh, KAN GEMM, ot-stage, coalesced copy-out
#pragma unroll
  for (int half = 0; half < 2; ++half) {
    // transform: V[ln][col*6 + c], per-uint XOR swizzle ((ln&7)<<3 on elem idx)
#pragma unroll
    for (int ms = 0; ms < 2; ++ms) {
      int mt = half * 2 + ms;
#pragma unroll
      for (int r = 0; r < 4; ++r) {
        float xv = acc2[mt][r] + buv;
        float sil = xv / (1.f + __expf(-xv));
        float b0[7], b1[6], b2[5];
#pragma unroll
        for (int q = 0; q < 7; ++q) b0[q] = (xv >= g[q] && xv < g[q + 1]) ? 1.f : 0.f;
#pragma unroll
        for (int q = 0; q < 6; ++q)
          b1[q] = (xv - g[q]) * r1[q] * b0[q] + (g[q + 2] - xv) * r1[q + 1] * b0[q + 1];
#pragma unroll
        for (int q = 0; q < 5; ++q)
          b2[q] = (xv - g[q]) * r2[q] * b1[q] + (g[q + 3] - xv) * r2[q + 1] * b1[q + 1];
        int ln = ms * 16 + lk * 4 + r;
        int base = ln * 384 + (w * 16 + lm) * 6;
        int sw = (ln & 7) << 3;
        *(unsigned*)&Vh[(base + 0) ^ sw] = pack_hi(sil, b2[0]);
        *(unsigned*)&Vh[(base + 2) ^ sw] = pack_hi(b2[1], b2[2]);
        *(unsigned*)&Vh[(base + 4) ^ sw] = pack_hi(b2[3], b2[4]);
      }
    }
    __syncthreads();  // V ready

    // KAN GEMM (1-term): wave w -> o-tile w, 2 s-tiles. B3 streamed from L2.
    f32x4 accK[2];
    accK[0] = (f32x4){0.f, 0.f, 0.f, 0.f};
    accK[1] = (f32x4){0.f, 0.f, 0.f, 0.f};
#pragma unroll
    for (int ks = 0; ks < 12; ++ks) {
      short8 bh = P3h[(w * 12 + ks) * 64 + l];
#pragma unroll
      for (int s = 0; s < 2; ++s) {
        int ri = ((s * 16 + lm) * 384 + ks * 32 + lk * 8) ^ swzA;
        short8 ah = *(const short8*)&Vh[ri];
        accK[s] = MFMA(ah, bh, accK[s]);
      }
    }
    __syncthreads();  // K: V reads done (ot overlays T-tail; transform of next half waits)

    // ---- stage out-half to LDS (f32, XOR swizzle)
#pragma unroll
    for (int s = 0; s < 2; ++s) {
      int o = w * 16 + lm;
#pragma unroll
      for (int r = 0; r < 4; ++r) {
        int ln = s * 16 + lk * 4 + r;
        ot[(ln * 64 + o) ^ ((ln & 7) << 3)] = accK[s][r];
      }
    }
    __syncthreads();  // O: ot ready

    // ---- coalesced copy-out: 8 threads x 32B per row, full 256B lines
    {
      int row2 = tid >> 3, c8 = (tid & 7) * 8;
      int node = half * 32 + row2;
      int n = n0 + node;
      if (n < NN) {
        int sw = (row2 & 7) << 3;
        float4 v0 = *(float4*)&ot[((row2 * 64 + c8) ^ sw)];
        float4 v1 = *(float4*)&ot[((row2 * 64 + c8 + 4) ^ sw)];
        if (degl[node] <= 0.f) {
          v0 = *(const float4*)(x + (size_t)n * 64 + c8);
          v1 = *(const float4*)(x + (size_t)n * 64 + c8 + 4);
        }
        *(float4*)(out + (size_t)n * 64 + c8) = v0;
        *(float4*)(out + (size_t)n * 64 + c8 + 4) = v1;
      }
    }
    __syncthreads();  // copy done before next half's transform/ot overwrite
  }
}

extern "C" void kernel_launch(void* const* d_in, const int* in_sizes, int n_in,
                              void* d_out, int out_size, void* d_ws, size_t ws_size,
                              hipStream_t stream) {
  const float* x        = (const float*)d_in[0];
  const float* contexts = (const float*)d_in[1];
  const float* attn     = (const float*)d_in[2];
  const int*   seg      = (const int*)d_in[3];
  const float* Wn       = (const float*)d_in[4];
  const float* bn       = (const float*)d_in[5];
  const float* Wc       = (const float*)d_in[6];
  const float* bc       = (const float*)d_in[7];
  const float* Wu       = (const float*)d_in[8];
  const float* bu       = (const float*)d_in[9];
  const float* base_w   = (const float*)d_in[10];
  const float* spline_w = (const float*)d_in[11];
  const float* scaler   = (const float*)d_in[12];
  const float* gridp    = (const float*)d_in[13];
  float* out = (float*)d_out;

  ushort_t* us  = (ushort_t*)d_ws;
  ushort_t* Sph = us;                    // 3,200,000
  ushort_t* p1h = Sph + 3200000;         // 16384
  ushort_t* p2h = p1h + 16384;           // 8192
  ushort_t* p3h = p2h + 8192;            // 24576
  float* aprime = (float*)(p3h + 24576); // 50,000
  float* degw   = aprime + 50000;        // 50,000
  int*   off    = (int*)(degw + 50000);  // 50,001

  kA_pack_off<<<3125, 256, 0, stream>>>(Wn, Wc, Wu, base_w, spline_w, scaler, seg,
                                        p1h, p2h, p3h, off);
  k1_edge_agg<<<12500, 256, 0, stream>>>(contexts, attn, off, Sph, aprime, degw);
  k234<<<782, 256, 0, stream>>>(x, Sph, aprime, degw, bn, bc, bu,
                                p1h, p2h, p3h, gridp, out);
}